// Round 11
// baseline (705.365 us; speedup 1.0000x reference)
//
#include <hip/hip_runtime.h>
#include <hip/hip_bf16.h>
#include <math.h>

#define N_USERS 100000
#define N_ITEMS 50000
#define N_NODES 150000
#define NNZ     4800000
#define EMB     64
#define BATCH   4096
#define REG_C   1e-5f

// coarse bucketed counting sort
#define ROWB    512                 // rows per bucket (row >> 9)
#define NBK     293                 // ceil(150000/512)
#define PADC    19456               // slots/bucket: mean 16382 + align waste 2051 + margin
#define CSTRIDE 16                  // one cursor per 64B line
#define P1_EPB  8192                // edges per block in pass 1
#define NB_P1   ((NNZ + P1_EPB - 1) / P1_EPB)   // 586
#define NB_PACK 2344                // N_NODES*8/2 items / 256
#define SENT    0x3FFFF             // sentinel col tag (real cols < 150000)

#define LROW    36                  // LDS row stride in uints (16B-aligned rows)

typedef short short8 __attribute__((ext_vector_type(8)));
typedef float f32x4  __attribute__((ext_vector_type(4)));
typedef float f32x2  __attribute__((ext_vector_type(2)));

static __device__ __forceinline__ unsigned short f2bf(float f) {
    unsigned u = __float_as_uint(f);
    u = u + 0x7FFFu + ((u >> 16) & 1u);
    return (unsigned short)(u >> 16);
}
static __device__ __forceinline__ unsigned pk2(float lo, float hi) {
    return (unsigned)f2bf(lo) | ((unsigned)f2bf(hi) << 16);
}
static __device__ __forceinline__ float blo(unsigned a) { return __uint_as_float(a << 16); }
static __device__ __forceinline__ float bhi(unsigned a) { return __uint_as_float(a & 0xFFFF0000u); }

// fp8 e4m3 (OCP) pack via HW converters
static __device__ __forceinline__ unsigned pkq4(float f0, float f1, float f2, float f3) {
    int v = __builtin_amdgcn_cvt_pk_fp8_f32(f0, f1, 0, false);
    v = __builtin_amdgcn_cvt_pk_fp8_f32(f2, f3, v, true);
    return (unsigned)v;
}

// nontemporal loads (pure streams: keep them from evicting L2 working set)
static __device__ __forceinline__ void eload(const int2* p_, int& c, float& v) {
    unsigned long long w = __builtin_nontemporal_load((const unsigned long long*)p_);
    c = (int)(unsigned)(w & 0xFFFFFFFFu);
    v = __int_as_float((int)(unsigned)(w >> 32));
}
static __device__ __forceinline__ int ntl(const int* p_) {
    return __builtin_nontemporal_load(p_);
}
static __device__ __forceinline__ float ntlf(const float* p_) {
    return __builtin_nontemporal_load(p_);
}

// ---------------- mega pass 1: bin edges + pack + acc0 (grid-fused) ---------
__global__ __launch_bounds__(256) void p1_bin_kernel(
    const int* __restrict__ rows, const int* __restrict__ cols,
    const float* __restrict__ vals, int* __restrict__ gcursor,
    int2* __restrict__ binned,
    const float* __restrict__ ue, const float* __restrict__ ie,
    unsigned int* __restrict__ xh, unsigned int* __restrict__ xq,
    const int* __restrict__ u, const int* __restrict__ ii,
    const int* __restrict__ jj,
    float* __restrict__ dui, float* __restrict__ duj, float* __restrict__ l2a) {
    __shared__ int hist[NBK];
    __shared__ int base[NBK];
    int t = threadIdx.x;
    int bid = blockIdx.x;

    if (bid >= NB_P1 + NB_PACK) {
        // ---- acc0 path: exact f32 dot/L2 of layer-0 embeddings ----
        int b = (bid - NB_P1 - NB_PACK) * 4 + (t >> 6);
        int lane = t & 63;
        float uv = ue[(size_t)u[b] * 64 + lane];
        float pv = ie[(size_t)ii[b] * 64 + lane];
        float nv = ie[(size_t)jj[b] * 64 + lane];
        float a = uv * pv, c = uv * nv, l = uv * uv + pv * pv + nv * nv;
        #pragma unroll
        for (int o = 32; o > 0; o >>= 1) {
            a += __shfl_xor(a, o, 64);
            c += __shfl_xor(c, o, 64);
            l += __shfl_xor(l, o, 64);
        }
        if (lane == 0) { dui[b] = a; duj[b] = c; l2a[b] = l; }
        return;
    }
    if (bid >= NB_P1) {
        // ---- pack path: ego -> Xh (bf16) + Xq (fp8), 2 groups/thread ----
        int g0 = ((bid - NB_P1) * 256 + t) * 2;
        #pragma unroll
        for (int g = g0; g < g0 + 2; ++g) {
            if (g >= N_NODES * 8) break;
            const float4* src;
            if (g < N_USERS * 8) src = (const float4*)ue + (size_t)g * 2;
            else src = (const float4*)ie + (size_t)(g - N_USERS * 8) * 2;
            float4 a = src[0], b = src[1];
            uint4 h;
            h.x = pk2(a.x, a.y); h.y = pk2(a.z, a.w);
            h.z = pk2(b.x, b.y); h.w = pk2(b.z, b.w);
            ((uint4*)xh)[g] = h;
            uint2 q;
            q.x = pkq4(a.x, a.y, a.z, a.w);
            q.y = pkq4(b.x, b.y, b.z, b.w);
            ((uint2*)xq)[g] = q;
        }
        return;
    }

    // ---- p1 path: LDS hist -> aligned reservation -> scatter -> fill ----
    int e0 = bid * P1_EPB;
    for (int b = t; b < NBK; b += 256) hist[b] = 0;
    __syncthreads();
    for (int i = 0; i < P1_EPB / 256; ++i) {
        int e = e0 + i * 256 + t;
        if (e < NNZ) atomicAdd(&hist[ntl(&rows[e]) >> 9], 1);
    }
    __syncthreads();
    for (int b = t; b < NBK; b += 256) {
        int h = hist[b];
        // 64B-aligned reservation: round to 8 records
        base[b] = (h > 0) ? atomicAdd(&gcursor[b * CSTRIDE], (h + 7) & ~7) : 0;
        hist[b] = 0;                        // reuse as rank counter
    }
    __syncthreads();
    for (int i = 0; i < P1_EPB / 256; ++i) {
        int e = e0 + i * 256 + t;
        if (e < NNZ) {
            int r = ntl(&rows[e]);
            int b = r >> 9;
            int rk = atomicAdd(&hist[b], 1);
            int rel = base[b] + rk;
            if (rel < PADC)                 // overflow guard (P ~ 0)
                binned[(size_t)b * PADC + rel] =
                    make_int2(ntl(&cols[e]) | ((r & 511) << 18),
                              __float_as_int(ntlf(&vals[e])));
        }
    }
    __syncthreads();
    // sentinel-fill alignment holes so every reserved line is fully written
    for (int b = t; b < NBK; b += 256) {
        int h = hist[b];
        if (h > 0) {
            int end = (h + 7) & ~7;
            for (int s = base[b] + h; s < base[b] + end && s < PADC; ++s)
                binned[(size_t)b * PADC + s] = make_int2(SENT, 0);
        }
    }
}

// ---------------- pass 2: per-bucket row sort via global scatter ------------
__global__ __launch_bounds__(256) void p2_sort_kernel(
    const int* __restrict__ gcursor, const int2* __restrict__ binned,
    int2* __restrict__ csr, int* __restrict__ start, int* __restrict__ cnt) {
    __shared__ int hist[ROWB];
    __shared__ int excl[ROWB];
    int b = blockIdx.x;
    int t = threadIdx.x;
    size_t bbase = (size_t)b * PADC;
    int n = gcursor[b * CSTRIDE];            // relative (includes align waste)
    if (n > PADC) n = PADC;
    hist[t] = 0; hist[t + 256] = 0;
    __syncthreads();
    for (int i = t; i < n; i += 256) {
        int c, rl; float v;
        eload(&binned[bbase + i], c, v);
        if ((c & 0x3FFFF) != SENT) atomicAdd(&hist[(c >> 18) & 511], 1);
    }
    __syncthreads();
    excl[t] = hist[t]; excl[t + 256] = hist[t + 256];
    __syncthreads();
    for (int o = 1; o < ROWB; o <<= 1) {           // Hillis-Steele inclusive, 512 wide
        int i1 = t + 256;
        int v0 = (t >= o) ? excl[t - o] : 0;
        int v1 = (i1 >= o) ? excl[i1 - o] : 0;
        __syncthreads();
        excl[t] += v0; excl[i1] += v1;
        __syncthreads();
    }
    int rowsInB = N_NODES - b * ROWB;
    if (rowsInB > ROWB) rowsInB = ROWB;
    for (int rr = t; rr < ROWB; rr += 256) {
        int s = excl[rr] - hist[rr];               // exclusive
        if (rr < rowsInB) {
            start[b * ROWB + rr] = (int)bbase + s;
            cnt[b * ROWB + rr]   = hist[rr];
        }
        excl[rr] = s;                              // becomes local cursor
    }
    __syncthreads();
    for (int i = t; i < n; i += 256) {
        int2 rec = binned[bbase + i];
        if ((rec.x & 0x3FFFF) == SENT) continue;
        int rl = (rec.x >> 18) & 511;
        int p = atomicAdd(&excl[rl], 1);
        csr[bbase + p] = make_int2(rec.x & 0x3FFFF, rec.y);
    }
}

// ---------------- CSR SpMM: wave/row, fp8 gathers (1 line/edge) -------------
__global__ __launch_bounds__(256) void spmm_csr_kernel(
    const int* __restrict__ start, const int* __restrict__ cnt,
    const int2* __restrict__ edges, const unsigned int* __restrict__ xq,
    float* __restrict__ out) {
    int row = blockIdx.x * 4 + (threadIdx.x >> 6);
    if (row >= N_NODES) return;
    int lane = threadIdx.x & 63;
    int eg = lane >> 4;
    int p  = lane & 15;
    int s = start[row];
    int n = cnt[row];
    float a0 = 0.f, a1 = 0.f, a2 = 0.f, a3 = 0.f;
    int k = 0;
    for (; k + 32 <= n; k += 32) {                  // unpredicated main: 8 gathers
        int c[8]; float v[8];
        #pragma unroll
        for (int j = 0; j < 8; ++j) eload(&edges[s + k + 4 * j + eg], c[j], v[j]);
        #pragma unroll
        for (int j = 0; j < 8; ++j) {
            unsigned q = xq[(size_t)c[j] * 16 + p];
            f32x2 lo = __builtin_amdgcn_cvt_pk_f32_fp8(q, false);
            f32x2 hi = __builtin_amdgcn_cvt_pk_f32_fp8(q, true);
            a0 = fmaf(v[j], lo[0], a0);
            a1 = fmaf(v[j], lo[1], a1);
            a2 = fmaf(v[j], hi[0], a2);
            a3 = fmaf(v[j], hi[1], a3);
        }
    }
    while (k < n) {                                 // predicated 16-edge blocks
        #pragma unroll
        for (int j = 0; j < 4; ++j) {
            int off = k + 4 * j + eg;
            bool valid = off < n;
            int c; float v;
            eload(&edges[s + (valid ? off : 0)], c, v);
            if (!valid) v = 0.f;
            unsigned q = xq[(size_t)c * 16 + p];
            f32x2 lo = __builtin_amdgcn_cvt_pk_f32_fp8(q, false);
            f32x2 hi = __builtin_amdgcn_cvt_pk_f32_fp8(q, true);
            a0 = fmaf(v, lo[0], a0);
            a1 = fmaf(v, lo[1], a1);
            a2 = fmaf(v, hi[0], a2);
            a3 = fmaf(v, hi[1], a3);
        }
        k += 16;
    }
    a0 += __shfl_xor(a0, 16, 64); a0 += __shfl_xor(a0, 32, 64);
    a1 += __shfl_xor(a1, 16, 64); a1 += __shfl_xor(a1, 32, 64);
    a2 += __shfl_xor(a2, 16, 64); a2 += __shfl_xor(a2, 32, 64);
    a3 += __shfl_xor(a3, 16, 64); a3 += __shfl_xor(a3, 32, 64);
    if (eg == 0)
        ((float4*)out)[(size_t)row * 16 + p] = make_float4(a0, a1, a2, a3);
}

// ---------------- dense: MFMA.  OUT = leakyrelu(SLI@W1 + PR@W2 + b) ---------
// In-place on xh/xq (each block touches only its own 64-row tile).
__global__ __launch_bounds__(256) void dense_kernel(
    unsigned int* xh, unsigned int* xq, const float* __restrict__ sideL,
    const float* __restrict__ W1, const float* __restrict__ b1,
    const float* __restrict__ W2, const float* __restrict__ b2)
{
    __shared__ unsigned asl[64 * LROW];   // SLI bf16 pairs
    __shared__ unsigned apr[64 * LROW];   // PR  bf16 pairs
    __shared__ unsigned wt1[64 * LROW];   // W1^T [n][k]; reused as out-stage
    __shared__ unsigned wt2[64 * LROW];   // W2^T [n][k]

    int t = threadIdx.x;
    int r0 = blockIdx.x * 64;

    // ---- stage W1/W2 transposed to bf16 [n][k] ----
    #pragma unroll
    for (int i = 0; i < 4; ++i) {
        int idx = i * 256 + t;               // 0..1023 float4s
        int kk = idx >> 4;                   // k row 0..63
        int ng = idx & 15;                   // col group: cols 4ng..4ng+3
        float4 w1v = ((const float4*)W1)[idx];
        float4 w2v = ((const float4*)W2)[idx];
        unsigned short* s1 = (unsigned short*)wt1;
        unsigned short* s2 = (unsigned short*)wt2;
        int c0 = 4 * ng;
        s1[(c0 + 0) * (2 * LROW) + kk] = f2bf(w1v.x);
        s1[(c0 + 1) * (2 * LROW) + kk] = f2bf(w1v.y);
        s1[(c0 + 2) * (2 * LROW) + kk] = f2bf(w1v.z);
        s1[(c0 + 3) * (2 * LROW) + kk] = f2bf(w1v.w);
        s2[(c0 + 0) * (2 * LROW) + kk] = f2bf(w2v.x);
        s2[(c0 + 1) * (2 * LROW) + kk] = f2bf(w2v.y);
        s2[(c0 + 2) * (2 * LROW) + kk] = f2bf(w2v.z);
        s2[(c0 + 3) * (2 * LROW) + kk] = f2bf(w2v.w);
    }

    // ---- stage SLI / PR (bf16 packed) ----
    #pragma unroll
    for (int i = 0; i < 2; ++i) {
        int q = i * 256 + t;                 // 0..511
        int row = q >> 3;                    // 0..63
        int u4 = q & 7;                      // uint4 within row
        uint4 h = make_uint4(0, 0, 0, 0);
        float4 s0 = make_float4(0.f, 0.f, 0.f, 0.f);
        float4 s1 = make_float4(0.f, 0.f, 0.f, 0.f);
        if (r0 + row < N_NODES) {
            h  = ((const uint4*)xh)[(size_t)(r0 + row) * 8 + u4];
            s0 = ((const float4*)sideL)[(size_t)(r0 + row) * 16 + 2 * u4];
            s1 = ((const float4*)sideL)[(size_t)(r0 + row) * 16 + 2 * u4 + 1];
        }
        float x0 = blo(h.x), x1 = bhi(h.x), x2 = blo(h.y), x3 = bhi(h.y);
        float x4 = blo(h.z), x5 = bhi(h.z), x6 = blo(h.w), x7 = bhi(h.w);
        uint4 sa, pa;
        sa.x = pk2(x0 + s0.x, x1 + s0.y); sa.y = pk2(x2 + s0.z, x3 + s0.w);
        sa.z = pk2(x4 + s1.x, x5 + s1.y); sa.w = pk2(x6 + s1.z, x7 + s1.w);
        pa.x = pk2(x0 * s0.x, x1 * s0.y); pa.y = pk2(x2 * s0.z, x3 * s0.w);
        pa.z = pk2(x4 * s1.x, x5 * s1.y); pa.w = pk2(x6 * s1.z, x7 * s1.w);
        *(uint4*)&asl[row * LROW + 4 * u4] = sa;
        *(uint4*)&apr[row * LROW + 4 * u4] = pa;
    }
    __syncthreads();

    // ---- MFMA phase ----
    int l = t & 63, wv = t >> 6;
    int q4 = l >> 4, mr = l & 15;
    int abase = (wv * 16 + mr) * LROW + 4 * q4;
    short8 aS0 = *(const short8*)&asl[abase];
    short8 aS1 = *(const short8*)&asl[abase + 16];
    short8 aP0 = *(const short8*)&apr[abase];
    short8 aP1 = *(const short8*)&apr[abase + 16];

    float lr[4][4];
    float rowss[4] = {0.f, 0.f, 0.f, 0.f};
    #pragma unroll
    for (int nb = 0; nb < 4; ++nb) {
        int wbase = (nb * 16 + mr) * LROW + 4 * q4;
        short8 b10 = *(const short8*)&wt1[wbase];
        short8 b11 = *(const short8*)&wt1[wbase + 16];
        short8 b20 = *(const short8*)&wt2[wbase];
        short8 b21 = *(const short8*)&wt2[wbase + 16];
        f32x4 acc = {0.f, 0.f, 0.f, 0.f};
        acc = __builtin_amdgcn_mfma_f32_16x16x32_bf16(aS0, b10, acc, 0, 0, 0);
        acc = __builtin_amdgcn_mfma_f32_16x16x32_bf16(aS1, b11, acc, 0, 0, 0);
        acc = __builtin_amdgcn_mfma_f32_16x16x32_bf16(aP0, b20, acc, 0, 0, 0);
        acc = __builtin_amdgcn_mfma_f32_16x16x32_bf16(aP1, b21, acc, 0, 0, 0);
        float bias = b1[nb * 16 + mr] + b2[nb * 16 + mr];
        #pragma unroll
        for (int r = 0; r < 4; ++r) {
            float v = acc[r] + bias;
            float lrv = v > 0.f ? v : 0.01f * v;
            lr[nb][r] = lrv;
            rowss[r] += lrv * lrv;
        }
    }
    #pragma unroll
    for (int o = 1; o < 16; o <<= 1) {
        #pragma unroll
        for (int r = 0; r < 4; ++r) rowss[r] += __shfl_xor(rowss[r], o, 64);
    }
    float inv[4];
    #pragma unroll
    for (int r = 0; r < 4; ++r) inv[r] = 1.f / fmaxf(sqrtf(rowss[r]), 1e-12f);

    __syncthreads();                         // all wt1/wt2 reads done
    unsigned short* os = (unsigned short*)wt1;
    #pragma unroll
    for (int nb = 0; nb < 4; ++nb) {
        #pragma unroll
        for (int r = 0; r < 4; ++r) {
            int rloc = wv * 16 + q4 * 4 + r;
            os[rloc * (2 * LROW) + nb * 16 + mr] = f2bf(lr[nb][r] * inv[r]);
        }
    }
    __syncthreads();

    // ---- coalesced writeback: bf16 + fp8 (in place) ----
    #pragma unroll
    for (int i = 0; i < 2; ++i) {
        int q = i * 256 + t;
        int row = q >> 3, u4 = q & 7;
        if (r0 + row < N_NODES) {
            uint4 h = *(const uint4*)&wt1[row * LROW + 4 * u4];
            ((uint4*)xh)[(size_t)(r0 + row) * 8 + u4] = h;
            uint2 qq;
            qq.x = pkq4(blo(h.x), bhi(h.x), blo(h.y), bhi(h.y));
            qq.y = pkq4(blo(h.z), bhi(h.z), blo(h.w), bhi(h.w));
            ((uint2*)xq)[(size_t)(r0 + row) * 8 + u4] = qq;
        }
    }
}

// ---------------- per-layer dot/L2 from bf16 embeddings ---------------------
__global__ void accB_kernel(const unsigned int* __restrict__ xh,
                            const int* __restrict__ u, const int* __restrict__ ii,
                            const int* __restrict__ jj,
                            float* __restrict__ dui, float* __restrict__ duj,
                            float* __restrict__ l2a) {
    int t = threadIdx.x;
    int lane = t & 63;
    int half = lane >> 5, p = lane & 31;
    int b = blockIdx.x * 8 + (t >> 6) * 2 + half;
    unsigned ua = xh[(size_t)u[b] * 32 + p];
    unsigned pa = xh[(size_t)(N_USERS + ii[b]) * 32 + p];
    unsigned na = xh[(size_t)(N_USERS + jj[b]) * 32 + p];
    float u0 = blo(ua), u1 = bhi(ua);
    float p0 = blo(pa), p1 = bhi(pa);
    float n0 = blo(na), n1 = bhi(na);
    float a = u0 * p0 + u1 * p1;
    float c = u0 * n0 + u1 * n1;
    float l = u0 * u0 + u1 * u1 + p0 * p0 + p1 * p1 + n0 * n0 + n1 * n1;
    #pragma unroll
    for (int o = 16; o > 0; o >>= 1) {       // reduce within each 32-lane half
        a += __shfl_xor(a, o, 64);
        c += __shfl_xor(c, o, 64);
        l += __shfl_xor(l, o, 64);
    }
    if (p == 0) { dui[b] += a; duj[b] += c; l2a[b] += l; }
}

// ---------------- final loss reduction --------------------------------------
__global__ void final_kernel(const float* __restrict__ dui, const float* __restrict__ duj,
                             const float* __restrict__ l2a, float* __restrict__ out) {
    __shared__ float sh[4];
    int t = threadIdx.x;
    float s = 0.f;
    for (int b = t; b < BATCH; b += 256) {
        float diff = dui[b] - duj[b];
        float ls = (diff >= 0.f) ? -log1pf(expf(-diff)) : (diff - log1pf(expf(diff)));
        s += -ls + REG_C * 0.5f * l2a[b];
    }
    #pragma unroll
    for (int o = 32; o > 0; o >>= 1) s += __shfl_xor(s, o, 64);
    int wave = t >> 6, lane = t & 63;
    if (lane == 0) sh[wave] = s;
    __syncthreads();
    if (t == 0) out[0] = (sh[0] + sh[1] + sh[2] + sh[3]) / (float)BATCH;
}

extern "C" void kernel_launch(void* const* d_in, const int* in_sizes, int n_in,
                              void* d_out, int out_size, void* d_ws, size_t ws_size,
                              hipStream_t stream) {
    const int*   rows     = (const int*)d_in[0];
    const int*   cols     = (const int*)d_in[1];
    const float* vals     = (const float*)d_in[2];
    const float* user_emb = (const float*)d_in[3];
    const float* item_emb = (const float*)d_in[4];
    const float* W_one    = (const float*)d_in[5];
    const float* b_one    = (const float*)d_in[6];
    const float* W_two    = (const float*)d_in[7];
    const float* b_two    = (const float*)d_in[8];
    const int*   u        = (const int*)d_in[9];
    const int*   ii       = (const int*)d_in[10];
    const int*   jj       = (const int*)d_in[11];

    // workspace (~121 MB).  B (f32 sideL, 38.4 MB) aliases binned (45.6 MB),
    // dead after p2_sort.  Xh/Xq in place across layers.
    unsigned int* Xh  = (unsigned int*)d_ws;                  // 19.2 MB bf16
    unsigned int* Xq  = Xh + (size_t)N_NODES * 32;            //  9.6 MB fp8
    int2* binned      = (int2*)(Xq + (size_t)N_NODES * 16);   // 45.6 MB
    float* B          = (float*)binned;                       // alias (post-p2)
    int2* csr         = binned + (size_t)NBK * PADC;          // 45.6 MB
    int*  gcursor     = (int*)(csr + (size_t)NBK * PADC);
    int*  startA      = gcursor + NBK * CSTRIDE;              // 150,016
    int*  cntA        = startA + 150016;                      // 150,016
    float* dui        = (float*)(cntA + 150016);              // 4096
    float* duj        = dui + BATCH;
    float* l2a        = duj + BATCH;

    (void)hipMemsetAsync(gcursor, 0, NBK * CSTRIDE * sizeof(int), stream);

    // mega pass 1: bin (586 blocks) + pack (2344) + acc0 (16)
    p1_bin_kernel<<<NB_P1 + NB_PACK + BATCH / 256 / 4 * 4 / 4, 256, 0, stream>>>(
        rows, cols, vals, gcursor, binned,
        user_emb, item_emb, Xh, Xq, u, ii, jj, dui, duj, l2a);
    p2_sort_kernel<<<NBK, 256, 0, stream>>>(gcursor, binned, csr, startA, cntA);

    for (int k = 0; k < 3; ++k) {
        spmm_csr_kernel<<<(N_NODES + 3) / 4, 256, 0, stream>>>(startA, cntA, csr, Xq, B);
        dense_kernel<<<(N_NODES + 63) / 64, 256, 0, stream>>>(
            Xh, Xq, B, W_one + k * 4096, b_one + k * 64,
            W_two + k * 4096, b_two + k * 64);
        accB_kernel<<<BATCH / 8, 256, 0, stream>>>(Xh, u, ii, jj, dui, duj, l2a);
    }

    final_kernel<<<1, 256, 0, stream>>>(dui, duj, l2a, (float*)d_out);
}

// Round 12
// 645.133 us; speedup vs baseline: 1.0934x; 1.0934x over previous
//
#include <hip/hip_runtime.h>
#include <hip/hip_bf16.h>
#include <math.h>

#define N_USERS 100000
#define N_ITEMS 50000
#define N_NODES 150000
#define NNZ     4800000
#define EMB     64
#define BATCH   4096
#define REG_C   1e-5f

// coarse bucketed counting sort
#define ROWB    512                 // rows per bucket (row >> 9)
#define NBK     293                 // ceil(150000/512)
#define PADC    17408               // slots/bucket = mean 16384 + 8 sigma
#define CSTRIDE 16                  // one cursor per 64B line
#define P1_EPB  8192                // edges per block in pass 1
#define NB_P1   ((NNZ + P1_EPB - 1) / P1_EPB)   // 586
#define NB_PACK 2344                // N_NODES*8 groups / (256*2)
#define NB_ACC0 1024                // BATCH/4

#define LROW    36                  // LDS row stride in uints (16B-aligned rows)

typedef short short8 __attribute__((ext_vector_type(8)));
typedef float f32x4  __attribute__((ext_vector_type(4)));
typedef float f32x2  __attribute__((ext_vector_type(2)));

static __device__ __forceinline__ unsigned short f2bf(float f) {
    unsigned u = __float_as_uint(f);
    u = u + 0x7FFFu + ((u >> 16) & 1u);
    return (unsigned short)(u >> 16);
}
static __device__ __forceinline__ unsigned pk2(float lo, float hi) {
    return (unsigned)f2bf(lo) | ((unsigned)f2bf(hi) << 16);
}
static __device__ __forceinline__ float blo(unsigned a) { return __uint_as_float(a << 16); }
static __device__ __forceinline__ float bhi(unsigned a) { return __uint_as_float(a & 0xFFFF0000u); }

// fp8 e4m3 (OCP) pack via HW converters
static __device__ __forceinline__ unsigned pkq4(float f0, float f1, float f2, float f3) {
    int v = __builtin_amdgcn_cvt_pk_fp8_f32(f0, f1, 0, false);
    v = __builtin_amdgcn_cvt_pk_fp8_f32(f2, f3, v, true);
    return (unsigned)v;
}

// nontemporal loads — ONLY for data read exactly once per kernel
static __device__ __forceinline__ void eload(const int2* p_, int& c, float& v) {
    unsigned long long w = __builtin_nontemporal_load((const unsigned long long*)p_);
    c = (int)(unsigned)(w & 0xFFFFFFFFu);
    v = __int_as_float((int)(unsigned)(w >> 32));
}
static __device__ __forceinline__ int ntl(const int* p_) {
    return __builtin_nontemporal_load(p_);
}
static __device__ __forceinline__ float ntlf(const float* p_) {
    return __builtin_nontemporal_load(p_);
}

// ---------------- mega pass 1: bin edges + pack + acc0 (grid-fused) ---------
__global__ __launch_bounds__(256) void p1_bin_kernel(
    const int* __restrict__ rows, const int* __restrict__ cols,
    const float* __restrict__ vals, int* __restrict__ gcursor,
    int2* __restrict__ binned,
    const float* __restrict__ ue, const float* __restrict__ ie,
    unsigned int* __restrict__ xh, unsigned int* __restrict__ xq,
    const int* __restrict__ u, const int* __restrict__ ii,
    const int* __restrict__ jj,
    float* __restrict__ dui, float* __restrict__ duj, float* __restrict__ l2a) {
    __shared__ int rowbuf[P1_EPB];     // 32 KB: rows staged once
    __shared__ int hist[NBK];
    __shared__ int base[NBK];
    int t = threadIdx.x;
    int bid = blockIdx.x;

    if (bid >= NB_P1 + NB_PACK) {
        // ---- acc0 path: exact f32 dot/L2 of layer-0 embeddings (4/block) ----
        int b = (bid - NB_P1 - NB_PACK) * 4 + (t >> 6);
        int lane = t & 63;
        float uv = ue[(size_t)u[b] * 64 + lane];
        float pv = ie[(size_t)ii[b] * 64 + lane];
        float nv = ie[(size_t)jj[b] * 64 + lane];
        float a = uv * pv, c = uv * nv, l = uv * uv + pv * pv + nv * nv;
        #pragma unroll
        for (int o = 32; o > 0; o >>= 1) {
            a += __shfl_xor(a, o, 64);
            c += __shfl_xor(c, o, 64);
            l += __shfl_xor(l, o, 64);
        }
        if (lane == 0) { dui[b] = a; duj[b] = c; l2a[b] = l; }
        return;
    }
    if (bid >= NB_P1) {
        // ---- pack path: ego -> Xh (bf16) + Xq (fp8), 2 groups/thread ----
        int g0 = ((bid - NB_P1) * 256 + t) * 2;
        #pragma unroll
        for (int g = g0; g < g0 + 2; ++g) {
            if (g >= N_NODES * 8) break;
            const float4* src;
            if (g < N_USERS * 8) src = (const float4*)ue + (size_t)g * 2;
            else src = (const float4*)ie + (size_t)(g - N_USERS * 8) * 2;
            float4 a = src[0], b = src[1];
            uint4 h;
            h.x = pk2(a.x, a.y); h.y = pk2(a.z, a.w);
            h.z = pk2(b.x, b.y); h.w = pk2(b.z, b.w);
            ((uint4*)xh)[g] = h;
            uint2 q;
            q.x = pkq4(a.x, a.y, a.z, a.w);
            q.y = pkq4(b.x, b.y, b.z, b.w);
            ((uint2*)xq)[g] = q;
        }
        return;
    }

    // ---- p1 path: rows->LDS once (NT), hist, reserve, scatter (NT streams) --
    int e0 = bid * P1_EPB;
    int nE = NNZ - e0; if (nE > P1_EPB) nE = P1_EPB;
    for (int i = t; i < nE; i += 256) rowbuf[i] = ntl(&rows[e0 + i]);
    for (int b = t; b < NBK; b += 256) hist[b] = 0;
    __syncthreads();
    for (int i = t; i < nE; i += 256) atomicAdd(&hist[rowbuf[i] >> 9], 1);
    __syncthreads();
    for (int b = t; b < NBK; b += 256) {
        int h = hist[b];
        base[b] = (h > 0) ? atomicAdd(&gcursor[b * CSTRIDE], h) : 0;
        hist[b] = 0;                        // reuse as rank counter
    }
    __syncthreads();
    for (int i = t; i < nE; i += 256) {
        int r = rowbuf[i];
        int b = r >> 9;
        int rk = atomicAdd(&hist[b], 1);
        int rel = base[b] + rk;
        if (rel < PADC)                     // overflow guard (P ~ 0)
            binned[(size_t)b * PADC + rel] =
                make_int2(ntl(&cols[e0 + i]) | ((r & 511) << 18),
                          __float_as_int(ntlf(&vals[e0 + i])));
    }
}

// ---------------- pass 2: per-bucket row sort via global scatter ------------
// binned is read twice -> plain loads (no NT).
__global__ __launch_bounds__(256) void p2_sort_kernel(
    const int* __restrict__ gcursor, const int2* __restrict__ binned,
    int2* __restrict__ csr, int* __restrict__ start, int* __restrict__ cnt) {
    __shared__ int hist[ROWB];
    __shared__ int excl[ROWB];
    int b = blockIdx.x;
    int t = threadIdx.x;
    size_t bbase = (size_t)b * PADC;
    int n = gcursor[b * CSTRIDE];
    if (n > PADC) n = PADC;
    hist[t] = 0; hist[t + 256] = 0;
    __syncthreads();
    for (int i = t; i < n; i += 256)
        atomicAdd(&hist[(binned[bbase + i].x >> 18) & 511], 1);
    __syncthreads();
    excl[t] = hist[t]; excl[t + 256] = hist[t + 256];
    __syncthreads();
    for (int o = 1; o < ROWB; o <<= 1) {           // Hillis-Steele inclusive, 512 wide
        int i1 = t + 256;
        int v0 = (t >= o) ? excl[t - o] : 0;
        int v1 = (i1 >= o) ? excl[i1 - o] : 0;
        __syncthreads();
        excl[t] += v0; excl[i1] += v1;
        __syncthreads();
    }
    int rowsInB = N_NODES - b * ROWB;
    if (rowsInB > ROWB) rowsInB = ROWB;
    for (int rr = t; rr < ROWB; rr += 256) {
        int s = excl[rr] - hist[rr];               // exclusive
        if (rr < rowsInB) {
            start[b * ROWB + rr] = (int)bbase + s;
            cnt[b * ROWB + rr]   = hist[rr];
        }
        excl[rr] = s;                              // becomes local cursor
    }
    __syncthreads();
    for (int i = t; i < n; i += 256) {
        int2 rec = binned[bbase + i];
        int rl = (rec.x >> 18) & 511;
        int p = atomicAdd(&excl[rl], 1);
        csr[bbase + p] = make_int2(rec.x & 0x3FFFF, rec.y);
    }
}

// ---------------- CSR SpMM: wave/row, fp8 gathers (1 line/edge) -------------
__global__ __launch_bounds__(256) void spmm_csr_kernel(
    const int* __restrict__ start, const int* __restrict__ cnt,
    const int2* __restrict__ edges, const unsigned int* __restrict__ xq,
    float* __restrict__ out) {
    int row = blockIdx.x * 4 + (threadIdx.x >> 6);
    if (row >= N_NODES) return;
    int lane = threadIdx.x & 63;
    int eg = lane >> 4;
    int p  = lane & 15;
    int s = start[row];
    int n = cnt[row];
    float a0 = 0.f, a1 = 0.f, a2 = 0.f, a3 = 0.f;
    int k = 0;
    for (; k + 32 <= n; k += 32) {                  // unpredicated main: 8 gathers
        int c[8]; float v[8];
        #pragma unroll
        for (int j = 0; j < 8; ++j) eload(&edges[s + k + 4 * j + eg], c[j], v[j]);
        #pragma unroll
        for (int j = 0; j < 8; ++j) {
            unsigned q = xq[(size_t)c[j] * 16 + p];
            f32x2 lo = __builtin_amdgcn_cvt_pk_f32_fp8(q, false);
            f32x2 hi = __builtin_amdgcn_cvt_pk_f32_fp8(q, true);
            a0 = fmaf(v[j], lo[0], a0);
            a1 = fmaf(v[j], lo[1], a1);
            a2 = fmaf(v[j], hi[0], a2);
            a3 = fmaf(v[j], hi[1], a3);
        }
    }
    while (k < n) {                                 // predicated 16-edge blocks
        #pragma unroll
        for (int j = 0; j < 4; ++j) {
            int off = k + 4 * j + eg;
            bool valid = off < n;
            int c; float v;
            eload(&edges[s + (valid ? off : 0)], c, v);
            if (!valid) v = 0.f;
            unsigned q = xq[(size_t)c * 16 + p];
            f32x2 lo = __builtin_amdgcn_cvt_pk_f32_fp8(q, false);
            f32x2 hi = __builtin_amdgcn_cvt_pk_f32_fp8(q, true);
            a0 = fmaf(v, lo[0], a0);
            a1 = fmaf(v, lo[1], a1);
            a2 = fmaf(v, hi[0], a2);
            a3 = fmaf(v, hi[1], a3);
        }
        k += 16;
    }
    a0 += __shfl_xor(a0, 16, 64); a0 += __shfl_xor(a0, 32, 64);
    a1 += __shfl_xor(a1, 16, 64); a1 += __shfl_xor(a1, 32, 64);
    a2 += __shfl_xor(a2, 16, 64); a2 += __shfl_xor(a2, 32, 64);
    a3 += __shfl_xor(a3, 16, 64); a3 += __shfl_xor(a3, 32, 64);
    if (eg == 0)
        ((float4*)out)[(size_t)row * 16 + p] = make_float4(a0, a1, a2, a3);
}

// ---------------- dense: MFMA.  OUT = leakyrelu(SLI@W1 + PR@W2 + b) ---------
// In-place on xh/xq (each block touches only its own 64-row tile).
__global__ __launch_bounds__(256) void dense_kernel(
    unsigned int* xh, unsigned int* xq, const float* __restrict__ sideL,
    const float* __restrict__ W1, const float* __restrict__ b1,
    const float* __restrict__ W2, const float* __restrict__ b2)
{
    __shared__ unsigned asl[64 * LROW];   // SLI bf16 pairs
    __shared__ unsigned apr[64 * LROW];   // PR  bf16 pairs
    __shared__ unsigned wt1[64 * LROW];   // W1^T [n][k]; reused as out-stage
    __shared__ unsigned wt2[64 * LROW];   // W2^T [n][k]

    int t = threadIdx.x;
    int r0 = blockIdx.x * 64;

    // ---- stage W1/W2 transposed to bf16 [n][k] ----
    #pragma unroll
    for (int i = 0; i < 4; ++i) {
        int idx = i * 256 + t;               // 0..1023 float4s
        int kk = idx >> 4;                   // k row 0..63
        int ng = idx & 15;                   // col group: cols 4ng..4ng+3
        float4 w1v = ((const float4*)W1)[idx];
        float4 w2v = ((const float4*)W2)[idx];
        unsigned short* s1 = (unsigned short*)wt1;
        unsigned short* s2 = (unsigned short*)wt2;
        int c0 = 4 * ng;
        s1[(c0 + 0) * (2 * LROW) + kk] = f2bf(w1v.x);
        s1[(c0 + 1) * (2 * LROW) + kk] = f2bf(w1v.y);
        s1[(c0 + 2) * (2 * LROW) + kk] = f2bf(w1v.z);
        s1[(c0 + 3) * (2 * LROW) + kk] = f2bf(w1v.w);
        s2[(c0 + 0) * (2 * LROW) + kk] = f2bf(w2v.x);
        s2[(c0 + 1) * (2 * LROW) + kk] = f2bf(w2v.y);
        s2[(c0 + 2) * (2 * LROW) + kk] = f2bf(w2v.z);
        s2[(c0 + 3) * (2 * LROW) + kk] = f2bf(w2v.w);
    }

    // ---- stage SLI / PR (bf16 packed) ----
    #pragma unroll
    for (int i = 0; i < 2; ++i) {
        int q = i * 256 + t;                 // 0..511
        int row = q >> 3;                    // 0..63
        int u4 = q & 7;                      // uint4 within row
        uint4 h = make_uint4(0, 0, 0, 0);
        float4 s0 = make_float4(0.f, 0.f, 0.f, 0.f);
        float4 s1 = make_float4(0.f, 0.f, 0.f, 0.f);
        if (r0 + row < N_NODES) {
            h  = ((const uint4*)xh)[(size_t)(r0 + row) * 8 + u4];
            s0 = ((const float4*)sideL)[(size_t)(r0 + row) * 16 + 2 * u4];
            s1 = ((const float4*)sideL)[(size_t)(r0 + row) * 16 + 2 * u4 + 1];
        }
        float x0 = blo(h.x), x1 = bhi(h.x), x2 = blo(h.y), x3 = bhi(h.y);
        float x4 = blo(h.z), x5 = bhi(h.z), x6 = blo(h.w), x7 = bhi(h.w);
        uint4 sa, pa;
        sa.x = pk2(x0 + s0.x, x1 + s0.y); sa.y = pk2(x2 + s0.z, x3 + s0.w);
        sa.z = pk2(x4 + s1.x, x5 + s1.y); sa.w = pk2(x6 + s1.z, x7 + s1.w);
        pa.x = pk2(x0 * s0.x, x1 * s0.y); pa.y = pk2(x2 * s0.z, x3 * s0.w);
        pa.z = pk2(x4 * s1.x, x5 * s1.y); pa.w = pk2(x6 * s1.z, x7 * s1.w);
        *(uint4*)&asl[row * LROW + 4 * u4] = sa;
        *(uint4*)&apr[row * LROW + 4 * u4] = pa;
    }
    __syncthreads();

    // ---- MFMA phase ----
    int l = t & 63, wv = t >> 6;
    int q4 = l >> 4, mr = l & 15;
    int abase = (wv * 16 + mr) * LROW + 4 * q4;
    short8 aS0 = *(const short8*)&asl[abase];
    short8 aS1 = *(const short8*)&asl[abase + 16];
    short8 aP0 = *(const short8*)&apr[abase];
    short8 aP1 = *(const short8*)&apr[abase + 16];

    float lr[4][4];
    float rowss[4] = {0.f, 0.f, 0.f, 0.f};
    #pragma unroll
    for (int nb = 0; nb < 4; ++nb) {
        int wbase = (nb * 16 + mr) * LROW + 4 * q4;
        short8 b10 = *(const short8*)&wt1[wbase];
        short8 b11 = *(const short8*)&wt1[wbase + 16];
        short8 b20 = *(const short8*)&wt2[wbase];
        short8 b21 = *(const short8*)&wt2[wbase + 16];
        f32x4 acc = {0.f, 0.f, 0.f, 0.f};
        acc = __builtin_amdgcn_mfma_f32_16x16x32_bf16(aS0, b10, acc, 0, 0, 0);
        acc = __builtin_amdgcn_mfma_f32_16x16x32_bf16(aS1, b11, acc, 0, 0, 0);
        acc = __builtin_amdgcn_mfma_f32_16x16x32_bf16(aP0, b20, acc, 0, 0, 0);
        acc = __builtin_amdgcn_mfma_f32_16x16x32_bf16(aP1, b21, acc, 0, 0, 0);
        float bias = b1[nb * 16 + mr] + b2[nb * 16 + mr];
        #pragma unroll
        for (int r = 0; r < 4; ++r) {
            float v = acc[r] + bias;
            float lrv = v > 0.f ? v : 0.01f * v;
            lr[nb][r] = lrv;
            rowss[r] += lrv * lrv;
        }
    }
    #pragma unroll
    for (int o = 1; o < 16; o <<= 1) {
        #pragma unroll
        for (int r = 0; r < 4; ++r) rowss[r] += __shfl_xor(rowss[r], o, 64);
    }
    float inv[4];
    #pragma unroll
    for (int r = 0; r < 4; ++r) inv[r] = 1.f / fmaxf(sqrtf(rowss[r]), 1e-12f);

    __syncthreads();                         // all wt1/wt2 reads done
    unsigned short* os = (unsigned short*)wt1;
    #pragma unroll
    for (int nb = 0; nb < 4; ++nb) {
        #pragma unroll
        for (int r = 0; r < 4; ++r) {
            int rloc = wv * 16 + q4 * 4 + r;
            os[rloc * (2 * LROW) + nb * 16 + mr] = f2bf(lr[nb][r] * inv[r]);
        }
    }
    __syncthreads();

    // ---- coalesced writeback: bf16 + fp8 (in place) ----
    #pragma unroll
    for (int i = 0; i < 2; ++i) {
        int q = i * 256 + t;
        int row = q >> 3, u4 = q & 7;
        if (r0 + row < N_NODES) {
            uint4 h = *(const uint4*)&wt1[row * LROW + 4 * u4];
            ((uint4*)xh)[(size_t)(r0 + row) * 8 + u4] = h;
            uint2 qq;
            qq.x = pkq4(blo(h.x), bhi(h.x), blo(h.y), bhi(h.y));
            qq.y = pkq4(blo(h.z), bhi(h.z), blo(h.w), bhi(h.w));
            ((uint2*)xq)[(size_t)(r0 + row) * 8 + u4] = qq;
        }
    }
}

// ---------------- per-layer dot/L2 from bf16 embeddings ---------------------
__global__ void accB_kernel(const unsigned int* __restrict__ xh,
                            const int* __restrict__ u, const int* __restrict__ ii,
                            const int* __restrict__ jj,
                            float* __restrict__ dui, float* __restrict__ duj,
                            float* __restrict__ l2a) {
    int t = threadIdx.x;
    int lane = t & 63;
    int half = lane >> 5, p = lane & 31;
    int b = blockIdx.x * 8 + (t >> 6) * 2 + half;
    unsigned ua = xh[(size_t)u[b] * 32 + p];
    unsigned pa = xh[(size_t)(N_USERS + ii[b]) * 32 + p];
    unsigned na = xh[(size_t)(N_USERS + jj[b]) * 32 + p];
    float u0 = blo(ua), u1 = bhi(ua);
    float p0 = blo(pa), p1 = bhi(pa);
    float n0 = blo(na), n1 = bhi(na);
    float a = u0 * p0 + u1 * p1;
    float c = u0 * n0 + u1 * n1;
    float l = u0 * u0 + u1 * u1 + p0 * p0 + p1 * p1 + n0 * n0 + n1 * n1;
    #pragma unroll
    for (int o = 16; o > 0; o >>= 1) {       // reduce within each 32-lane half
        a += __shfl_xor(a, o, 64);
        c += __shfl_xor(c, o, 64);
        l += __shfl_xor(l, o, 64);
    }
    if (p == 0) { dui[b] += a; duj[b] += c; l2a[b] += l; }
}

// ---------------- final loss reduction --------------------------------------
__global__ void final_kernel(const float* __restrict__ dui, const float* __restrict__ duj,
                             const float* __restrict__ l2a, float* __restrict__ out) {
    __shared__ float sh[4];
    int t = threadIdx.x;
    float s = 0.f;
    for (int b = t; b < BATCH; b += 256) {
        float diff = dui[b] - duj[b];
        float ls = (diff >= 0.f) ? -log1pf(expf(-diff)) : (diff - log1pf(expf(diff)));
        s += -ls + REG_C * 0.5f * l2a[b];
    }
    #pragma unroll
    for (int o = 32; o > 0; o >>= 1) s += __shfl_xor(s, o, 64);
    int wave = t >> 6, lane = t & 63;
    if (lane == 0) sh[wave] = s;
    __syncthreads();
    if (t == 0) out[0] = (sh[0] + sh[1] + sh[2] + sh[3]) / (float)BATCH;
}

extern "C" void kernel_launch(void* const* d_in, const int* in_sizes, int n_in,
                              void* d_out, int out_size, void* d_ws, size_t ws_size,
                              hipStream_t stream) {
    const int*   rows     = (const int*)d_in[0];
    const int*   cols     = (const int*)d_in[1];
    const float* vals     = (const float*)d_in[2];
    const float* user_emb = (const float*)d_in[3];
    const float* item_emb = (const float*)d_in[4];
    const float* W_one    = (const float*)d_in[5];
    const float* b_one    = (const float*)d_in[6];
    const float* W_two    = (const float*)d_in[7];
    const float* b_two    = (const float*)d_in[8];
    const int*   u        = (const int*)d_in[9];
    const int*   ii       = (const int*)d_in[10];
    const int*   jj       = (const int*)d_in[11];

    // workspace (~112 MB).  B (f32 sideL, 38.4 MB) aliases binned (40.8 MB),
    // dead after p2_sort.  Xh/Xq in place across layers.
    unsigned int* Xh  = (unsigned int*)d_ws;                  // 19.2 MB bf16
    unsigned int* Xq  = Xh + (size_t)N_NODES * 32;            //  9.6 MB fp8
    int2* binned      = (int2*)(Xq + (size_t)N_NODES * 16);   // 40.8 MB
    float* B          = (float*)binned;                       // alias (post-p2)
    int2* csr         = binned + (size_t)NBK * PADC;          // 40.8 MB
    int*  gcursor     = (int*)(csr + (size_t)NBK * PADC);
    int*  startA      = gcursor + NBK * CSTRIDE;              // 150,016
    int*  cntA        = startA + 150016;                      // 150,016
    float* dui        = (float*)(cntA + 150016);              // 4096
    float* duj        = dui + BATCH;
    float* l2a        = duj + BATCH;

    (void)hipMemsetAsync(gcursor, 0, NBK * CSTRIDE * sizeof(int), stream);

    // mega pass 1: bin (586 blocks) + pack (2344) + acc0 (1024)
    p1_bin_kernel<<<NB_P1 + NB_PACK + NB_ACC0, 256, 0, stream>>>(
        rows, cols, vals, gcursor, binned,
        user_emb, item_emb, Xh, Xq, u, ii, jj, dui, duj, l2a);
    p2_sort_kernel<<<NBK, 256, 0, stream>>>(gcursor, binned, csr, startA, cntA);

    for (int k = 0; k < 3; ++k) {
        spmm_csr_kernel<<<(N_NODES + 3) / 4, 256, 0, stream>>>(startA, cntA, csr, Xq, B);
        dense_kernel<<<(N_NODES + 63) / 64, 256, 0, stream>>>(
            Xh, Xq, B, W_one + k * 4096, b_one + k * 64,
            W_two + k * 4096, b_two + k * 64);
        accB_kernel<<<BATCH / 8, 256, 0, stream>>>(Xh, u, ii, jj, dui, duj, l2a);
    }

    final_kernel<<<1, 256, 0, stream>>>(dui, duj, l2a, (float*)d_out);
}